// Round 1
// baseline (1236.387 us; speedup 1.0000x reference)
//
#include <hip/hip_runtime.h>
#include <hip/hip_bf16.h>
#include <math.h>
#include <stddef.h>

#define BATCH   2
#define SEQLEN  2048
#define DMODEL  1024
#define DINNER  2048
#define DSTATE  16
#define DCONV   4
#define DTRANK  64
#define NROWS   (BATCH*SEQLEN)   // 4096

using ab_frag = __attribute__((ext_vector_type(8))) short;   // 8 bf16 (4 VGPRs)
using cd_frag = __attribute__((ext_vector_type(4))) float;   // 4 fp32

__device__ __forceinline__ unsigned short f2bf(float f) {
    unsigned u = __float_as_uint(f);
    u = (u + 0x7FFFu + ((u >> 16) & 1u)) >> 16;
    return (unsigned short)u;
}

// ---------------- fp32 -> bf16 convert (4 elems/thread) ----------------
__global__ void cvt_f32_bf16(const float* __restrict__ src,
                             unsigned short* __restrict__ dst, int n4) {
    int i = blockIdx.x * blockDim.x + threadIdx.x;
    if (i < n4) {
        float4 v = ((const float4*)src)[i];
        ushort4 o;
        o.x = f2bf(v.x); o.y = f2bf(v.y); o.z = f2bf(v.z); o.w = f2bf(v.w);
        ((ushort4*)dst)[i] = o;
    }
}

// ---------------- generic NT bf16 MFMA GEMM: C[M][N] = A[M][K] * W[N][K]^T ----
// 128x128 tile, BK=32, 256 threads (4 waves, each a 64x64 quadrant of 4x4 MFMAs)
#define LDSP 40   // LDS row pitch in ushorts (32 + 8 pad)
__global__ __launch_bounds__(256) void gemm_bf16_nt(
    const unsigned short* __restrict__ A, int lda,
    const unsigned short* __restrict__ W, int ldw,
    float* __restrict__ C, int ldc,
    int M, int N, int K)
{
    __shared__ unsigned short As[128 * LDSP];
    __shared__ unsigned short Ws[128 * LDSP];
    const int tid  = threadIdx.x;
    const int lane = tid & 63;
    const int wave = tid >> 6;
    const int l15  = lane & 15;
    const int quad = lane >> 4;
    const int wrow = (wave >> 1) * 64;
    const int wcol = (wave & 1) * 64;
    const int mBase = blockIdx.y * 128;
    const int nBase = blockIdx.x * 128;

    cd_frag acc[4][4];
#pragma unroll
    for (int i = 0; i < 4; ++i)
#pragma unroll
        for (int j = 0; j < 4; ++j)
            acc[i][j] = (cd_frag){0.f, 0.f, 0.f, 0.f};

    for (int kBase = 0; kBase < K; kBase += 32) {
        // stage A tile (rows always valid: M is a multiple of 128)
#pragma unroll
        for (int p = 0; p < 2; ++p) {
            int c   = tid + p * 256;       // 0..511, 8 bf16 per chunk
            int row = c >> 2;              // 0..127
            int kq  = (c & 3) << 3;        // 0,8,16,24
            ab_frag v = *(const ab_frag*)(A + (size_t)(mBase + row) * lda + kBase + kq);
            *(ab_frag*)(&As[row * LDSP + kq]) = v;
        }
        // stage W tile (guard rows vs N)
#pragma unroll
        for (int p = 0; p < 2; ++p) {
            int c   = tid + p * 256;
            int row = c >> 2;
            int kq  = (c & 3) << 3;
            ab_frag v = {0, 0, 0, 0, 0, 0, 0, 0};
            if (nBase + row < N)
                v = *(const ab_frag*)(W + (size_t)(nBase + row) * ldw + kBase + kq);
            *(ab_frag*)(&Ws[row * LDSP + kq]) = v;
        }
        __syncthreads();

        ab_frag af[4], bfr[4];
#pragma unroll
        for (int i = 0; i < 4; ++i) {
            af[i]  = *(const ab_frag*)(&As[(wrow + i * 16 + l15) * LDSP + quad * 8]);
            bfr[i] = *(const ab_frag*)(&Ws[(wcol + i * 16 + l15) * LDSP + quad * 8]);
        }
#pragma unroll
        for (int mi = 0; mi < 4; ++mi)
#pragma unroll
            for (int ni = 0; ni < 4; ++ni)
                acc[mi][ni] = __builtin_amdgcn_mfma_f32_16x16x32_bf16(
                    af[mi], bfr[ni], acc[mi][ni], 0, 0, 0);
        __syncthreads();
    }

    // epilogue: C/D layout col=lane&15, row=quad*4+reg  [m89-verified]
#pragma unroll
    for (int mi = 0; mi < 4; ++mi)
#pragma unroll
        for (int ni = 0; ni < 4; ++ni) {
            int r0 = mBase + wrow + mi * 16 + quad * 4;
            int cc = nBase + wcol + ni * 16 + l15;
            if (cc < N) {
#pragma unroll
                for (int rg = 0; rg < 4; ++rg)
                    C[(size_t)(r0 + rg) * ldc + cc] = acc[mi][ni][rg];
            }
        }
}

// ---------------- depthwise causal conv (K=4) + SiLU ----------------
__global__ void conv_silu_kernel(const float* __restrict__ xz,
                                 const float* __restrict__ cw,
                                 const float* __restrict__ cb,
                                 float* __restrict__ xc) {
    int idx = blockIdx.x * 256 + threadIdx.x;     // 2^23 threads: [b][l][d]
    int d = idx & (DINNER - 1);
    int l = (idx >> 11) & (SEQLEN - 1);
    int b = idx >> 22;
    const float* base = xz + (size_t)b * SEQLEN * (2 * DINNER);
    float s = cb[d];
#pragma unroll
    for (int k = 0; k < DCONV; ++k) {
        int ll = l - (DCONV - 1) + k;
        if (ll >= 0) s += base[(size_t)ll * (2 * DINNER) + d] * cw[d * DCONV + k];
    }
    xc[idx] = s / (1.f + __expf(-s));
}

// ---------------- bias + softplus on delta ----------------
__global__ void softplus_bias(float* __restrict__ delta,
                              const float* __restrict__ bias) {
    int idx = blockIdx.x * 256 + threadIdx.x;
    int d = idx & (DINNER - 1);
    float x = delta[idx] + bias[d];
    delta[idx] = (x > 20.f) ? x : log1pf(__expf(x));
}

// ---------------- selective scan: thread per (b,d,n), shfl-reduce over n ----
__global__ __launch_bounds__(256) void scan_kernel(
    const float* __restrict__ delta, const float* __restrict__ xc,
    const float* __restrict__ xdbl, const float* __restrict__ A_log,
    const float* __restrict__ Dv, float* __restrict__ y /* ld 4096 */)
{
    int b    = blockIdx.y;
    int dgrp = blockIdx.x;            // 0..127
    int tid  = threadIdx.x;
    int n  = tid & 15;
    int dd = tid >> 4;                // 0..15
    int d  = dgrp * 16 + dd;
    float Adn = -__expf(A_log[d * 16 + n]);
    float Dd  = Dv[d];
    float h = 0.f;
    const float* dl = delta + (size_t)b * SEQLEN * DINNER + d;
    const float* uc = xc    + (size_t)b * SEQLEN * DINNER + d;
    const float* bc = xdbl  + (size_t)b * SEQLEN * 96 + 64 + n;
    float* yo = y + (size_t)b * SEQLEN * 4096 + d;
    for (int t = 0; t < SEQLEN; ++t) {
        float dv = dl[(size_t)t * DINNER];
        float u  = uc[(size_t)t * DINNER];
        float Bv = bc[(size_t)t * 96];
        float Cv = bc[(size_t)t * 96 + 16];
        float dA = __expf(dv * Adn);
        h = h * dA + dv * u * Bv;
        float p = h * Cv;
        p += __shfl_xor(p, 1, 64);
        p += __shfl_xor(p, 2, 64);
        p += __shfl_xor(p, 4, 64);
        p += __shfl_xor(p, 8, 64);
        if (n == 0) yo[(size_t)t * 4096] = p + Dd * u;
    }
}

// ---------------- y * silu(z), output bf16 for out_proj GEMM ----------------
__global__ void gate_cvt(const float* __restrict__ xz,
                         unsigned short* __restrict__ yb) {
    int idx = blockIdx.x * 256 + threadIdx.x;     // [row=b*L+l][d]
    int d = idx & (DINNER - 1);
    int row = idx >> 11;
    float yv = xz[(size_t)row * 4096 + d];
    float z  = xz[(size_t)row * 4096 + 2048 + d];
    float g  = z / (1.f + __expf(-z));
    yb[idx] = f2bf(yv * g);
}

extern "C" void kernel_launch(void* const* d_in, const int* in_sizes, int n_in,
                              void* d_out, int out_size, void* d_ws, size_t ws_size,
                              hipStream_t stream) {
    const float* hidden    = (const float*)d_in[0];
    const float* in_proj_w = (const float*)d_in[1];
    const float* conv_w    = (const float*)d_in[2];
    const float* conv_b    = (const float*)d_in[3];
    const float* x_proj_w  = (const float*)d_in[4];
    const float* dt_proj_w = (const float*)d_in[5];
    const float* dt_proj_b = (const float*)d_in[6];
    const float* A_log     = (const float*)d_in[7];
    const float* Dvec      = (const float*)d_in[8];
    const float* out_proj_w= (const float*)d_in[9];
    float* out = (float*)d_out;

    char* ws = (char*)d_ws;
    float* xz      = (float*)(ws + 0);              // 4096*4096 f32 (x | z)
    float* xconv   = (float*)(ws + 67108864);       // 4096*2048 f32
    float* delta   = (float*)(ws + 100663296);      // 4096*2048 f32
    float* xdbl    = (float*)(ws + 134217728);      // 4096*96  f32
    unsigned short* hbf    = (unsigned short*)(ws + 135790592); // 4096*1024
    unsigned short* w1bf   = (unsigned short*)(ws + 144179200); // 4096*1024
    unsigned short* xcbf   = (unsigned short*)(ws + 152567808); // 4096*2048
    unsigned short* xpwbf  = (unsigned short*)(ws + 169345024); // 96*2048
    unsigned short* xdblbf = (unsigned short*)(ws + 169738240); // 4096*96
    unsigned short* dtwbf  = (unsigned short*)(ws + 170524672); // 2048*64
    unsigned short* outwbf = (unsigned short*)(ws + 170786816); // 1024*2048
    unsigned short* ygbf   = (unsigned short*)(ws + 174981120); // 4096*2048

    auto cvt = [&](const float* s, unsigned short* dst, int n) {
        int n4 = n / 4;
        cvt_f32_bf16<<<dim3((n4 + 255) / 256), dim3(256), 0, stream>>>(s, dst, n4);
    };

    cvt(hidden,     hbf,    4096 * 1024);
    cvt(in_proj_w,  w1bf,   4096 * 1024);
    cvt(out_proj_w, outwbf, 1024 * 2048);

    // xz = hidden @ in_proj_w.T   (M=4096, N=4096, K=1024)
    gemm_bf16_nt<<<dim3(32, 32), 256, 0, stream>>>(hbf, 1024, w1bf, 1024,
                                                   xz, 4096, 4096, 4096, 1024);
    // conv + silu -> xconv
    conv_silu_kernel<<<32768, 256, 0, stream>>>(xz, conv_w, conv_b, xconv);

    cvt(xconv,    xcbf,  4096 * 2048);
    cvt(x_proj_w, xpwbf, 96 * 2048);
    // x_dbl = xconv @ x_proj_w.T  (M=4096, N=96, K=2048)
    gemm_bf16_nt<<<dim3(1, 32), 256, 0, stream>>>(xcbf, 2048, xpwbf, 2048,
                                                  xdbl, 96, 4096, 96, 2048);

    cvt(xdbl,      xdblbf, 4096 * 96);
    cvt(dt_proj_w, dtwbf,  2048 * 64);
    // delta_raw = dt @ dt_proj_w.T (M=4096, N=2048, K=64; A is first 64 cols of xdbl, lda=96)
    gemm_bf16_nt<<<dim3(16, 32), 256, 0, stream>>>(xdblbf, 96, dtwbf, 64,
                                                   delta, 2048, 4096, 2048, 64);
    softplus_bias<<<32768, 256, 0, stream>>>(delta, dt_proj_b);

    // selective scan -> y written into x-half of xz (ld 4096)
    scan_kernel<<<dim3(128, 2), 256, 0, stream>>>(delta, xconv, xdbl, A_log, Dvec, xz);

    // y * silu(z) -> bf16
    gate_cvt<<<32768, 256, 0, stream>>>(xz, ygbf);

    // out = y_gated @ out_proj_w.T (M=4096, N=1024, K=2048)
    gemm_bf16_nt<<<dim3(8, 32), 256, 0, stream>>>(ygbf, 2048, outwbf, 2048,
                                                  out, 1024, 4096, 1024, 2048);
}

// Round 2
// 565.113 us; speedup vs baseline: 2.1879x; 2.1879x over previous
//
#include <hip/hip_runtime.h>
#include <hip/hip_bf16.h>
#include <math.h>
#include <stddef.h>

#define BATCH   2
#define SEQLEN  2048
#define DMODEL  1024
#define DINNER  2048
#define DSTATE  16
#define DCONV   4
#define DTRANK  64
#define NROWS   (BATCH*SEQLEN)   // 4096
#define LCH     128              // scan chunk length
#define NCH     (SEQLEN/LCH)     // 16 chunks

using ab_frag = __attribute__((ext_vector_type(8))) short;   // 8 bf16 (4 VGPRs)
using cd_frag = __attribute__((ext_vector_type(4))) float;   // 4 fp32

__device__ __forceinline__ unsigned short f2bf(float f) {
    unsigned u = __float_as_uint(f);
    u = (u + 0x7FFFu + ((u >> 16) & 1u)) >> 16;
    return (unsigned short)u;
}

// ---------------- fp32 -> bf16 convert (4 elems/thread) ----------------
__global__ void cvt_f32_bf16(const float* __restrict__ src,
                             unsigned short* __restrict__ dst, int n4) {
    int i = blockIdx.x * blockDim.x + threadIdx.x;
    if (i < n4) {
        float4 v = ((const float4*)src)[i];
        ushort4 o;
        o.x = f2bf(v.x); o.y = f2bf(v.y); o.z = f2bf(v.z); o.w = f2bf(v.w);
        ((ushort4*)dst)[i] = o;
    }
}

// ---------------- generic NT bf16 MFMA GEMM: C[M][N] = A[M][K] * W[N][K]^T ----
// 128x128 tile, BK=32, 256 threads (4 waves, each a 64x64 quadrant of 4x4 MFMAs)
#define LDSP 40   // LDS row pitch in ushorts (32 + 8 pad)
__global__ __launch_bounds__(256) void gemm_bf16_nt(
    const unsigned short* __restrict__ A, int lda,
    const unsigned short* __restrict__ W, int ldw,
    float* __restrict__ C, int ldc,
    int M, int N, int K)
{
    __shared__ unsigned short As[128 * LDSP];
    __shared__ unsigned short Ws[128 * LDSP];
    const int tid  = threadIdx.x;
    const int lane = tid & 63;
    const int wave = tid >> 6;
    const int l15  = lane & 15;
    const int quad = lane >> 4;
    const int wrow = (wave >> 1) * 64;
    const int wcol = (wave & 1) * 64;
    const int mBase = blockIdx.y * 128;
    const int nBase = blockIdx.x * 128;

    cd_frag acc[4][4];
#pragma unroll
    for (int i = 0; i < 4; ++i)
#pragma unroll
        for (int j = 0; j < 4; ++j)
            acc[i][j] = (cd_frag){0.f, 0.f, 0.f, 0.f};

    for (int kBase = 0; kBase < K; kBase += 32) {
#pragma unroll
        for (int p = 0; p < 2; ++p) {
            int c   = tid + p * 256;       // 0..511, 8 bf16 per chunk
            int row = c >> 2;              // 0..127
            int kq  = (c & 3) << 3;        // 0,8,16,24
            ab_frag v = *(const ab_frag*)(A + (size_t)(mBase + row) * lda + kBase + kq);
            *(ab_frag*)(&As[row * LDSP + kq]) = v;
        }
#pragma unroll
        for (int p = 0; p < 2; ++p) {
            int c   = tid + p * 256;
            int row = c >> 2;
            int kq  = (c & 3) << 3;
            ab_frag v = {0, 0, 0, 0, 0, 0, 0, 0};
            if (nBase + row < N)
                v = *(const ab_frag*)(W + (size_t)(nBase + row) * ldw + kBase + kq);
            *(ab_frag*)(&Ws[row * LDSP + kq]) = v;
        }
        __syncthreads();

        ab_frag af[4], bfr[4];
#pragma unroll
        for (int i = 0; i < 4; ++i) {
            af[i]  = *(const ab_frag*)(&As[(wrow + i * 16 + l15) * LDSP + quad * 8]);
            bfr[i] = *(const ab_frag*)(&Ws[(wcol + i * 16 + l15) * LDSP + quad * 8]);
        }
#pragma unroll
        for (int mi = 0; mi < 4; ++mi)
#pragma unroll
            for (int ni = 0; ni < 4; ++ni)
                acc[mi][ni] = __builtin_amdgcn_mfma_f32_16x16x32_bf16(
                    af[mi], bfr[ni], acc[mi][ni], 0, 0, 0);
        __syncthreads();
    }

#pragma unroll
    for (int mi = 0; mi < 4; ++mi)
#pragma unroll
        for (int ni = 0; ni < 4; ++ni) {
            int r0 = mBase + wrow + mi * 16 + quad * 4;
            int cc = nBase + wcol + ni * 16 + l15;
            if (cc < N) {
#pragma unroll
                for (int rg = 0; rg < 4; ++rg)
                    C[(size_t)(r0 + rg) * ldc + cc] = acc[mi][ni][rg];
            }
        }
}

// ---------------- depthwise causal conv (K=4) + SiLU ----------------
__global__ void conv_silu_kernel(const float* __restrict__ xz,
                                 const float* __restrict__ cw,
                                 const float* __restrict__ cb,
                                 float* __restrict__ xc) {
    int idx = blockIdx.x * 256 + threadIdx.x;     // 2^23 threads: [b][l][d]
    int d = idx & (DINNER - 1);
    int l = (idx >> 11) & (SEQLEN - 1);
    int b = idx >> 22;
    const float* base = xz + (size_t)b * SEQLEN * (2 * DINNER);
    float s = cb[d];
#pragma unroll
    for (int k = 0; k < DCONV; ++k) {
        int ll = l - (DCONV - 1) + k;
        if (ll >= 0) s += base[(size_t)ll * (2 * DINNER) + d] * cw[d * DCONV + k];
    }
    xc[idx] = s / (1.f + __expf(-s));
}

// ---------------- bias + softplus on delta ----------------
__global__ void softplus_bias(float* __restrict__ delta,
                              const float* __restrict__ bias) {
    int idx = blockIdx.x * 256 + threadIdx.x;
    int d = idx & (DINNER - 1);
    float x = delta[idx] + bias[d];
    delta[idx] = (x > 20.f) ? x : log1pf(__expf(x));
}

// ---------------- chunked selective scan ----------------
// Phase 1: per (b,d,n,chunk) local scan with h0=0 -> S (chunk-final state),
//          P = exp(Adn * sum(dv)) (chunk decay).
__global__ __launch_bounds__(256) void scan_phase1(
    const float* __restrict__ delta, const float* __restrict__ xc,
    const float* __restrict__ xdbl, const float* __restrict__ A_log,
    float* __restrict__ S, float* __restrict__ P)
{
    int ch   = blockIdx.x;            // 0..NCH-1
    int dgrp = blockIdx.y;            // 0..127
    int b    = blockIdx.z;
    int tid  = threadIdx.x;
    int n  = tid & 15;
    int dd = tid >> 4;
    int d  = dgrp * 16 + dd;
    float Adn = -__expf(A_log[d * 16 + n]);
    float h = 0.f, dsum = 0.f;
    int t0 = ch * LCH;
    const float* dl = delta + ((size_t)b * SEQLEN + t0) * DINNER + d;
    const float* uc = xc    + ((size_t)b * SEQLEN + t0) * DINNER + d;
    const float* bc = xdbl  + ((size_t)b * SEQLEN + t0) * 96 + 64 + n;
#pragma unroll 4
    for (int t = 0; t < LCH; ++t) {
        float dv = dl[(size_t)t * DINNER];
        float u  = uc[(size_t)t * DINNER];
        float Bv = bc[(size_t)t * 96];
        float dA = __expf(dv * Adn);
        h = h * dA + dv * u * Bv;
        dsum += dv;
    }
    size_t idx = (((size_t)b * NCH + ch) << 15) + (d << 4) + n;
    S[idx] = h;
    P[idx] = __expf(Adn * dsum);
}

// Phase 2: sequential scan over the 16 chunk boundaries; H[c] = state entering chunk c.
__global__ void scan_phase2(const float* __restrict__ S,
                            const float* __restrict__ P,
                            float* __restrict__ H) {
    int i  = blockIdx.x * 256 + threadIdx.x;   // 0..65535 = (b, d*16+n)
    int b  = i >> 15;
    int dn = i & 32767;
    float h = 0.f;
    for (int c = 0; c < NCH; ++c) {
        size_t idx = (((size_t)b * NCH + c) << 15) + dn;
        H[idx] = h;
        h = S[idx] + P[idx] * h;
    }
}

// Phase 3: re-run each chunk from H, emit y (ld 4096).
__global__ __launch_bounds__(256) void scan_phase3(
    const float* __restrict__ delta, const float* __restrict__ xc,
    const float* __restrict__ xdbl, const float* __restrict__ A_log,
    const float* __restrict__ Dv, const float* __restrict__ H,
    float* __restrict__ y)
{
    int ch   = blockIdx.x;
    int dgrp = blockIdx.y;
    int b    = blockIdx.z;
    int tid  = threadIdx.x;
    int n  = tid & 15;
    int dd = tid >> 4;
    int d  = dgrp * 16 + dd;
    float Adn = -__expf(A_log[d * 16 + n]);
    float Dd  = Dv[d];
    size_t idx = (((size_t)b * NCH + ch) << 15) + (d << 4) + n;
    float h = H[idx];
    int t0 = ch * LCH;
    const float* dl = delta + ((size_t)b * SEQLEN + t0) * DINNER + d;
    const float* uc = xc    + ((size_t)b * SEQLEN + t0) * DINNER + d;
    const float* bc = xdbl  + ((size_t)b * SEQLEN + t0) * 96 + 64 + n;
    float* yo = y + ((size_t)b * SEQLEN + t0) * 4096 + d;
#pragma unroll 2
    for (int t = 0; t < LCH; ++t) {
        float dv = dl[(size_t)t * DINNER];
        float u  = uc[(size_t)t * DINNER];
        float Bv = bc[(size_t)t * 96];
        float Cv = bc[(size_t)t * 96 + 16];
        float dA = __expf(dv * Adn);
        h = h * dA + dv * u * Bv;
        float p = h * Cv;
        p += __shfl_xor(p, 1, 64);
        p += __shfl_xor(p, 2, 64);
        p += __shfl_xor(p, 4, 64);
        p += __shfl_xor(p, 8, 64);
        if (n == 0) yo[(size_t)t * 4096] = p + Dd * u;
    }
}

// ---------------- y * silu(z), output bf16 for out_proj GEMM ----------------
__global__ void gate_cvt(const float* __restrict__ xz,
                         unsigned short* __restrict__ yb) {
    int idx = blockIdx.x * 256 + threadIdx.x;     // [row=b*L+l][d]
    int d = idx & (DINNER - 1);
    int row = idx >> 11;
    float yv = xz[(size_t)row * 4096 + d];
    float z  = xz[(size_t)row * 4096 + 2048 + d];
    float g  = z / (1.f + __expf(-z));
    yb[idx] = f2bf(yv * g);
}

extern "C" void kernel_launch(void* const* d_in, const int* in_sizes, int n_in,
                              void* d_out, int out_size, void* d_ws, size_t ws_size,
                              hipStream_t stream) {
    const float* hidden    = (const float*)d_in[0];
    const float* in_proj_w = (const float*)d_in[1];
    const float* conv_w    = (const float*)d_in[2];
    const float* conv_b    = (const float*)d_in[3];
    const float* x_proj_w  = (const float*)d_in[4];
    const float* dt_proj_w = (const float*)d_in[5];
    const float* dt_proj_b = (const float*)d_in[6];
    const float* A_log     = (const float*)d_in[7];
    const float* Dvec      = (const float*)d_in[8];
    const float* out_proj_w= (const float*)d_in[9];
    float* out = (float*)d_out;

    char* ws = (char*)d_ws;
    float* xz      = (float*)(ws + 0);              // 4096*4096 f32 (x | z)
    float* xconv   = (float*)(ws + 67108864);       // 4096*2048 f32
    float* delta   = (float*)(ws + 100663296);      // 4096*2048 f32
    float* xdbl    = (float*)(ws + 134217728);      // 4096*96  f32
    unsigned short* hbf    = (unsigned short*)(ws + 135790592); // 4096*1024 (dead after GEMM1)
    unsigned short* w1bf   = (unsigned short*)(ws + 144179200); // 4096*1024 (dead after GEMM1)
    unsigned short* xcbf   = (unsigned short*)(ws + 152567808); // 4096*2048
    unsigned short* xpwbf  = (unsigned short*)(ws + 169345024); // 96*2048
    unsigned short* xdblbf = (unsigned short*)(ws + 169738240); // 4096*96
    unsigned short* dtwbf  = (unsigned short*)(ws + 170524672); // 2048*64
    unsigned short* outwbf = (unsigned short*)(ws + 170786816); // 1024*2048
    unsigned short* ygbf   = (unsigned short*)(ws + 174981120); // 4096*2048
    // scan scratch reuses hbf/w1bf regions (dead after GEMM1): 4 MB each
    float* Sbuf = (float*)(ws + 135790592);         // 2*16*2048*16 f32 = 4 MB
    float* Pbuf = (float*)(ws + 139984896);         // 4 MB
    float* Hbuf = (float*)(ws + 144179200);         // 4 MB

    auto cvt = [&](const float* s, unsigned short* dst, int n) {
        int n4 = n / 4;
        cvt_f32_bf16<<<dim3((n4 + 255) / 256), dim3(256), 0, stream>>>(s, dst, n4);
    };

    cvt(hidden,     hbf,    4096 * 1024);
    cvt(in_proj_w,  w1bf,   4096 * 1024);
    cvt(out_proj_w, outwbf, 1024 * 2048);

    // xz = hidden @ in_proj_w.T   (M=4096, N=4096, K=1024)
    gemm_bf16_nt<<<dim3(32, 32), 256, 0, stream>>>(hbf, 1024, w1bf, 1024,
                                                   xz, 4096, 4096, 4096, 1024);
    // conv + silu -> xconv
    conv_silu_kernel<<<32768, 256, 0, stream>>>(xz, conv_w, conv_b, xconv);

    cvt(xconv,    xcbf,  4096 * 2048);
    cvt(x_proj_w, xpwbf, 96 * 2048);
    // x_dbl = xconv @ x_proj_w.T  (M=4096, N=96, K=2048)
    gemm_bf16_nt<<<dim3(1, 32), 256, 0, stream>>>(xcbf, 2048, xpwbf, 2048,
                                                  xdbl, 96, 4096, 96, 2048);

    cvt(xdbl,      xdblbf, 4096 * 96);
    cvt(dt_proj_w, dtwbf,  2048 * 64);
    // delta_raw = dt @ dt_proj_w.T (M=4096, N=2048, K=64)
    gemm_bf16_nt<<<dim3(16, 32), 256, 0, stream>>>(xdblbf, 96, dtwbf, 64,
                                                   delta, 2048, 4096, 2048, 64);
    softplus_bias<<<32768, 256, 0, stream>>>(delta, dt_proj_b);

    // chunked selective scan -> y written into x-half of xz (ld 4096)
    scan_phase1<<<dim3(NCH, 128, BATCH), 256, 0, stream>>>(delta, xconv, xdbl,
                                                           A_log, Sbuf, Pbuf);
    scan_phase2<<<dim3(256), 256, 0, stream>>>(Sbuf, Pbuf, Hbuf);
    scan_phase3<<<dim3(NCH, 128, BATCH), 256, 0, stream>>>(delta, xconv, xdbl,
                                                           A_log, Dvec, Hbuf, xz);

    // y * silu(z) -> bf16
    gate_cvt<<<32768, 256, 0, stream>>>(xz, ygbf);

    // out = y_gated @ out_proj_w.T (M=4096, N=1024, K=2048)
    gemm_bf16_nt<<<dim3(8, 32), 256, 0, stream>>>(ygbf, 2048, outwbf, 2048,
                                                  out, 1024, 4096, 1024, 2048);
}

// Round 3
// 409.215 us; speedup vs baseline: 3.0214x; 1.3810x over previous
//
#include <hip/hip_runtime.h>
#include <hip/hip_bf16.h>
#include <math.h>
#include <stddef.h>

#define BATCH   2
#define SEQLEN  2048
#define DMODEL  1024
#define DINNER  2048
#define DSTATE  16
#define DCONV   4
#define DTRANK  64
#define NROWS   (BATCH*SEQLEN)   // 4096
#define LCH     32               // scan chunk length
#define NCH     (SEQLEN/LCH)     // 64 chunks

using ab_frag = __attribute__((ext_vector_type(8))) short;   // 8 bf16 (4 VGPRs)
using cd_frag = __attribute__((ext_vector_type(4))) float;   // 4 fp32

__device__ __forceinline__ unsigned short f2bf(float f) {
    unsigned u = __float_as_uint(f);
    u = (u + 0x7FFFu + ((u >> 16) & 1u)) >> 16;
    return (unsigned short)u;
}

// ---------------- fp32 -> bf16 convert (4 elems/thread) ----------------
__global__ void cvt_f32_bf16(const float* __restrict__ src,
                             unsigned short* __restrict__ dst, int n4) {
    int i = blockIdx.x * blockDim.x + threadIdx.x;
    if (i < n4) {
        float4 v = ((const float4*)src)[i];
        ushort4 o;
        o.x = f2bf(v.x); o.y = f2bf(v.y); o.z = f2bf(v.z); o.w = f2bf(v.w);
        ((ushort4*)dst)[i] = o;
    }
}

__global__ void zero_f32(float* __restrict__ p, int n) {
    int i = blockIdx.x * 256 + threadIdx.x;
    if (i < n) p[i] = 0.f;
}

// ---------------- generic NT bf16 MFMA GEMM: C[M][N] = A[M][K] * W[N][K]^T ----
// 128x128 tile, BK=32, 256 threads (4 waves, each a 64x64 quadrant of 4x4 MFMAs)
// EPI: 0 = plain store, 1 = atomicAdd (split-K), 2 = softplus(acc+bias[col]),
//      3 = xz split (col<2048 -> C, else C2), both ld 2048
#define LDSP 40   // LDS row pitch in ushorts (32 + 8 pad)
template<int EPI>
__global__ __launch_bounds__(256) void gemm_bf16_nt(
    const unsigned short* __restrict__ A, int lda,
    const unsigned short* __restrict__ W, int ldw,
    float* __restrict__ C, int ldc,
    int M, int N, int K, int kOff,
    float* __restrict__ C2, const float* __restrict__ bias)
{
    __shared__ unsigned short As[128 * LDSP];
    __shared__ unsigned short Ws[128 * LDSP];
    const int tid  = threadIdx.x;
    const int lane = tid & 63;
    const int wave = tid >> 6;
    const int l15  = lane & 15;
    const int quad = lane >> 4;
    const int wrow = (wave >> 1) * 64;
    const int wcol = (wave & 1) * 64;
    const int mBase = blockIdx.y * 128;
    const int nBase = blockIdx.x * 128;
    const int kStart = kOff + blockIdx.z * K;

    cd_frag acc[4][4];
#pragma unroll
    for (int i = 0; i < 4; ++i)
#pragma unroll
        for (int j = 0; j < 4; ++j)
            acc[i][j] = (cd_frag){0.f, 0.f, 0.f, 0.f};

    for (int kBase = kStart; kBase < kStart + K; kBase += 32) {
#pragma unroll
        for (int p = 0; p < 2; ++p) {
            int c   = tid + p * 256;       // 0..511, 8 bf16 per chunk
            int row = c >> 2;              // 0..127
            int kq  = (c & 3) << 3;        // 0,8,16,24
            ab_frag v = *(const ab_frag*)(A + (size_t)(mBase + row) * lda + kBase + kq);
            *(ab_frag*)(&As[row * LDSP + kq]) = v;
        }
#pragma unroll
        for (int p = 0; p < 2; ++p) {
            int c   = tid + p * 256;
            int row = c >> 2;
            int kq  = (c & 3) << 3;
            ab_frag v = {0, 0, 0, 0, 0, 0, 0, 0};
            if (nBase + row < N)
                v = *(const ab_frag*)(W + (size_t)(nBase + row) * ldw + kBase + kq);
            *(ab_frag*)(&Ws[row * LDSP + kq]) = v;
        }
        __syncthreads();

        ab_frag af[4], bfr[4];
#pragma unroll
        for (int i = 0; i < 4; ++i) {
            af[i]  = *(const ab_frag*)(&As[(wrow + i * 16 + l15) * LDSP + quad * 8]);
            bfr[i] = *(const ab_frag*)(&Ws[(wcol + i * 16 + l15) * LDSP + quad * 8]);
        }
#pragma unroll
        for (int mi = 0; mi < 4; ++mi)
#pragma unroll
            for (int ni = 0; ni < 4; ++ni)
                acc[mi][ni] = __builtin_amdgcn_mfma_f32_16x16x32_bf16(
                    af[mi], bfr[ni], acc[mi][ni], 0, 0, 0);
        __syncthreads();
    }

    // epilogue: C/D layout col=lane&15, row=quad*4+reg  [m89-verified]
#pragma unroll
    for (int mi = 0; mi < 4; ++mi)
#pragma unroll
        for (int ni = 0; ni < 4; ++ni) {
            int r0 = mBase + wrow + mi * 16 + quad * 4;
            int cc = nBase + wcol + ni * 16 + l15;
            if (cc < N) {
#pragma unroll
                for (int rg = 0; rg < 4; ++rg) {
                    float v = acc[mi][ni][rg];
                    size_t r = (size_t)(r0 + rg);
                    if (EPI == 0) {
                        C[r * ldc + cc] = v;
                    } else if (EPI == 1) {
                        atomicAdd(&C[r * ldc + cc], v);
                    } else if (EPI == 2) {
                        float x = v + bias[cc];
                        C[r * ldc + cc] = (x > 20.f) ? x : log1pf(__expf(x));
                    } else {
                        if (cc < 2048) C[r * 2048 + cc] = v;
                        else           C2[r * 2048 + (cc - 2048)] = v;
                    }
                }
            }
        }
}

// ---------------- depthwise causal conv (K=4) + SiLU, emits f32 + bf16 ------
__global__ void conv_silu_kernel(const float* __restrict__ xbuf,
                                 const float* __restrict__ cw,
                                 const float* __restrict__ cb,
                                 float* __restrict__ xc,
                                 unsigned short* __restrict__ xcbf) {
    int idx = blockIdx.x * 256 + threadIdx.x;     // [b][l][d]
    int d = idx & (DINNER - 1);
    int l = (idx >> 11) & (SEQLEN - 1);
    int b = idx >> 22;
    const float* base = xbuf + (size_t)b * SEQLEN * DINNER;
    float s = cb[d];
#pragma unroll
    for (int k = 0; k < DCONV; ++k) {
        int ll = l - (DCONV - 1) + k;
        if (ll >= 0) s += base[(size_t)ll * DINNER + d] * cw[d * DCONV + k];
    }
    float v = s / (1.f + __expf(-s));
    xc[idx] = v;
    xcbf[idx] = f2bf(v);
}

// ---------------- chunked selective scan, thread = (b, chunk, d) ------------
// All 16 n-states live in registers; no cross-lane ops.
// S/P/H layout: [b][ch][n][d] -> idx = ((b*NCH+ch)*16+n)*2048 + d (d coalesced)
__global__ __launch_bounds__(256) void scan_phase1(
    const float* __restrict__ delta, const float* __restrict__ xc,
    const float* __restrict__ xdbl, const float* __restrict__ A_log,
    float* __restrict__ S, float* __restrict__ P)
{
    int d  = blockIdx.x * 256 + threadIdx.x;   // 0..2047
    int ch = blockIdx.y;
    int b  = blockIdx.z;
    const float4* ap = (const float4*)(A_log + (size_t)d * 16);
    float Adn[16];
#pragma unroll
    for (int j = 0; j < 4; ++j) {
        float4 a = ap[j];
        Adn[4*j+0] = -__expf(a.x); Adn[4*j+1] = -__expf(a.y);
        Adn[4*j+2] = -__expf(a.z); Adn[4*j+3] = -__expf(a.w);
    }
    float h[16];
#pragma unroll
    for (int n = 0; n < 16; ++n) h[n] = 0.f;
    float dsum = 0.f;
    int t0 = ch * LCH;
    const float* dl = delta + ((size_t)b * SEQLEN + t0) * DINNER + d;
    const float* uc = xc    + ((size_t)b * SEQLEN + t0) * DINNER + d;
    const float* bc = xdbl  + ((size_t)b * SEQLEN + t0) * 96 + 64;
    for (int t = 0; t < LCH; ++t) {
        float dv = dl[(size_t)t * DINNER];
        float u  = uc[(size_t)t * DINNER];
        const float4* bp = (const float4*)(bc + (size_t)t * 96);
        float4 B0 = bp[0], B1 = bp[1], B2 = bp[2], B3 = bp[3];
        float Bv[16] = {B0.x,B0.y,B0.z,B0.w, B1.x,B1.y,B1.z,B1.w,
                        B2.x,B2.y,B2.z,B2.w, B3.x,B3.y,B3.z,B3.w};
        float du = dv * u;
        dsum += dv;
#pragma unroll
        for (int n = 0; n < 16; ++n)
            h[n] = h[n] * __expf(dv * Adn[n]) + du * Bv[n];
    }
    size_t base = ((size_t)(b * NCH + ch) * 16) << 11;
#pragma unroll
    for (int n = 0; n < 16; ++n) {
        S[base + ((size_t)n << 11) + d] = h[n];
        P[base + ((size_t)n << 11) + d] = __expf(dsum * Adn[n]);
    }
}

// Phase 2: sequential scan over chunk boundaries; H[c] = state entering chunk c.
__global__ void scan_phase2(const float* __restrict__ S,
                            const float* __restrict__ P,
                            float* __restrict__ H) {
    int i = blockIdx.x * 256 + threadIdx.x;   // 0..65535 = (b, n, d)
    int b = i >> 15;
    int n = (i >> 11) & 15;
    int d = i & 2047;
    float h = 0.f;
    for (int c = 0; c < NCH; ++c) {
        size_t idx = (((size_t)((b * NCH + c) * 16 + n)) << 11) + d;
        H[idx] = h;
        h = S[idx] + P[idx] * h;
    }
}

// Phase 3: re-run each chunk from H, fuse D*u, silu(z) gate, bf16 output.
__global__ __launch_bounds__(256) void scan_phase3(
    const float* __restrict__ delta, const float* __restrict__ xc,
    const float* __restrict__ xdbl, const float* __restrict__ A_log,
    const float* __restrict__ Dv, const float* __restrict__ H,
    const float* __restrict__ zbuf, unsigned short* __restrict__ yg)
{
    int d  = blockIdx.x * 256 + threadIdx.x;
    int ch = blockIdx.y;
    int b  = blockIdx.z;
    const float4* ap = (const float4*)(A_log + (size_t)d * 16);
    float Adn[16];
#pragma unroll
    for (int j = 0; j < 4; ++j) {
        float4 a = ap[j];
        Adn[4*j+0] = -__expf(a.x); Adn[4*j+1] = -__expf(a.y);
        Adn[4*j+2] = -__expf(a.z); Adn[4*j+3] = -__expf(a.w);
    }
    float Dd = Dv[d];
    size_t hbase = ((size_t)(b * NCH + ch) * 16) << 11;
    float h[16];
#pragma unroll
    for (int n = 0; n < 16; ++n) h[n] = H[hbase + ((size_t)n << 11) + d];
    int t0 = ch * LCH;
    const float* dl = delta + ((size_t)b * SEQLEN + t0) * DINNER + d;
    const float* uc = xc    + ((size_t)b * SEQLEN + t0) * DINNER + d;
    const float* zl = zbuf  + ((size_t)b * SEQLEN + t0) * DINNER + d;
    const float* bc = xdbl  + ((size_t)b * SEQLEN + t0) * 96 + 64;
    unsigned short* yo = yg + ((size_t)b * SEQLEN + t0) * DINNER + d;
    for (int t = 0; t < LCH; ++t) {
        float dv = dl[(size_t)t * DINNER];
        float u  = uc[(size_t)t * DINNER];
        const float4* bp = (const float4*)(bc + (size_t)t * 96);
        float4 B0 = bp[0], B1 = bp[1], B2 = bp[2], B3 = bp[3];
        float4 C0 = bp[4], C1 = bp[5], C2 = bp[6], C3 = bp[7];
        float Bv[16] = {B0.x,B0.y,B0.z,B0.w, B1.x,B1.y,B1.z,B1.w,
                        B2.x,B2.y,B2.z,B2.w, B3.x,B3.y,B3.z,B3.w};
        float Cv[16] = {C0.x,C0.y,C0.z,C0.w, C1.x,C1.y,C1.z,C1.w,
                        C2.x,C2.y,C2.z,C2.w, C3.x,C3.y,C3.z,C3.w};
        float du = dv * u;
#pragma unroll
        for (int n = 0; n < 16; ++n)
            h[n] = h[n] * __expf(dv * Adn[n]) + du * Bv[n];
        float y0 = 0.f, y1 = 0.f, y2 = 0.f, y3 = 0.f;
#pragma unroll
        for (int n = 0; n < 16; n += 4) {
            y0 += h[n+0] * Cv[n+0];
            y1 += h[n+1] * Cv[n+1];
            y2 += h[n+2] * Cv[n+2];
            y3 += h[n+3] * Cv[n+3];
        }
        float y = (y0 + y1) + (y2 + y3) + Dd * u;
        float z = zl[(size_t)t * DINNER];
        float g = z / (1.f + __expf(-z));
        yo[(size_t)t * DINNER] = f2bf(y * g);
    }
}

extern "C" void kernel_launch(void* const* d_in, const int* in_sizes, int n_in,
                              void* d_out, int out_size, void* d_ws, size_t ws_size,
                              hipStream_t stream) {
    const float* hidden    = (const float*)d_in[0];
    const float* in_proj_w = (const float*)d_in[1];
    const float* conv_w    = (const float*)d_in[2];
    const float* conv_b    = (const float*)d_in[3];
    const float* x_proj_w  = (const float*)d_in[4];
    const float* dt_proj_w = (const float*)d_in[5];
    const float* dt_proj_b = (const float*)d_in[6];
    const float* A_log     = (const float*)d_in[7];
    const float* Dvec      = (const float*)d_in[8];
    const float* out_proj_w= (const float*)d_in[9];
    float* out = (float*)d_out;

    char* ws = (char*)d_ws;
    float* xbuf  = (float*)(ws + 0);           // 32 MB, x plane (dead after conv)
    float* Sbuf  = (float*)(ws + 0);           // 16 MB (reuses xbuf)
    float* Pbuf  = (float*)(ws + 16777216);    // 16 MB (reuses xbuf)
    float* zbuf  = (float*)(ws + 33554432);    // 32 MB, z plane (live to phase3)
    float* xconv = (float*)(ws + 67108864);    // 32 MB
    float* delta = (float*)(ws + 100663296);   // 32 MB
    float* xdbl  = (float*)(ws + 134217728);   // 1.5 MB
    unsigned short* hbf    = (unsigned short*)(ws + 135790592); // 8 MB (dead after GEMM1)
    float*          Hbuf   = (float*)         (ws + 135790592); // 16 MB (reuses hbf+w1bf)
    unsigned short* w1bf   = (unsigned short*)(ws + 144179200); // 8 MB (dead after GEMM1)
    unsigned short* xcbf   = (unsigned short*)(ws + 152567808); // 16 MB
    unsigned short* xpwbf  = (unsigned short*)(ws + 169345024); // 384 KB
    unsigned short* xdblbf = (unsigned short*)(ws + 169738240); // 768 KB
    unsigned short* dtwbf  = (unsigned short*)(ws + 170524672); // 256 KB
    unsigned short* outwbf = (unsigned short*)(ws + 170786816); // 4 MB
    unsigned short* ygbf   = (unsigned short*)(ws + 174981120); // 16 MB

    auto cvt = [&](const float* s, unsigned short* dst, int n) {
        int n4 = n / 4;
        cvt_f32_bf16<<<dim3((n4 + 255) / 256), dim3(256), 0, stream>>>(s, dst, n4);
    };

    cvt(hidden,     hbf,    4096 * 1024);
    cvt(in_proj_w,  w1bf,   4096 * 1024);
    cvt(out_proj_w, outwbf, 1024 * 2048);
    cvt(x_proj_w,   xpwbf,  96 * 2048);
    cvt(dt_proj_w,  dtwbf,  2048 * 64);

    // GEMM1: xz = hidden @ in_proj_w.T (M=4096,N=4096,K=1024), split x|z planes
    gemm_bf16_nt<3><<<dim3(32, 32), 256, 0, stream>>>(
        hbf, 1024, w1bf, 1024, xbuf, 2048, 4096, 4096, 1024, 0, zbuf, nullptr);

    // conv + silu -> xconv (f32) + xcbf (bf16)
    conv_silu_kernel<<<32768, 256, 0, stream>>>(xbuf, conv_w, conv_b, xconv, xcbf);

    // GEMM2: x_dbl = xconv @ x_proj_w.T (M=4096,N=96,K=2048), split-K x8 atomic
    zero_f32<<<1536, 256, 0, stream>>>(xdbl, 4096 * 96);
    gemm_bf16_nt<1><<<dim3(1, 32, 8), 256, 0, stream>>>(
        xcbf, 2048, xpwbf, 2048, xdbl, 96, 4096, 96, 256, 0, nullptr, nullptr);

    cvt(xdbl, xdblbf, 4096 * 96);

    // GEMM3: delta = softplus(dt @ dt_proj_w.T + bias) (M=4096,N=2048,K=64)
    gemm_bf16_nt<2><<<dim3(16, 32), 256, 0, stream>>>(
        xdblbf, 96, dtwbf, 64, delta, 2048, 4096, 2048, 64, 0, nullptr, dt_proj_b);

    // chunked selective scan + fused gate -> ygbf (bf16)
    scan_phase1<<<dim3(8, NCH, BATCH), 256, 0, stream>>>(delta, xconv, xdbl,
                                                         A_log, Sbuf, Pbuf);
    scan_phase2<<<dim3(256), 256, 0, stream>>>(Sbuf, Pbuf, Hbuf);
    scan_phase3<<<dim3(8, NCH, BATCH), 256, 0, stream>>>(delta, xconv, xdbl,
                                                         A_log, Dvec, Hbuf, zbuf, ygbf);

    // GEMM4: out = y_gated @ out_proj_w.T (M=4096,N=1024,K=2048)
    gemm_bf16_nt<0><<<dim3(8, 32), 256, 0, stream>>>(
        ygbf, 2048, outwbf, 2048, out, 1024, 4096, 1024, 2048, 0, nullptr, nullptr);
}